// Round 9
// baseline (198.079 us; speedup 1.0000x reference)
//
#include <hip/hip_runtime.h>
#include <hip/hip_bf16.h>

#define DEV __device__ __forceinline__

typedef short bf16x8 __attribute__((ext_vector_type(8)));
typedef float f32x4 __attribute__((ext_vector_type(4)));
typedef unsigned int u32;
typedef unsigned int u32x4 __attribute__((ext_vector_type(4)));

constexpr int BB = 2, SS = 2048, DD = 1024, HH = 16, DHD = 64;
constexpr int MM = BB * SS; // 4096
#define QSC 0.1803368801111f  /* 0.125 * log2(e): scores in log2 domain */

#if __has_builtin(__builtin_amdgcn_exp2f)
#define EXP2(x) __builtin_amdgcn_exp2f(x)
#else
#define EXP2(x) exp2f(x)
#endif

// round-half-up bf16; bias only at exact-half cases
DEV unsigned short f2bf(float f) {
    union { float f; unsigned int u; } v; v.f = f;
    return (unsigned short)((v.u + 0x8000u) >> 16);
}
// pack two f32 -> (bf16(b)<<16)|bf16(a) : add, add, v_perm = 3 instr
#if __has_builtin(__builtin_amdgcn_perm)
DEV u32 pk2bf(float a, float b) {
    union { float f; u32 u; } ua, ub; ua.f = a; ub.f = b;
    return __builtin_amdgcn_perm(ub.u + 0x8000u, ua.u + 0x8000u, 0x07060302u);
}
#else
DEV u32 pk2bf(float a, float b) {
    union { float f; u32 u; } ua, ub; ua.f = a; ub.f = b;
    return ((ua.u + 0x8000u) >> 16) | ((ub.u + 0x8000u) & 0xffff0000u);
}
#endif

// single-instruction RNE pack (gfx950 has no builtin; inline asm per T12)
DEV u32 cvtpk2bf(float a, float b) {
    u32 r;
    asm("v_cvt_pk_bf16_f32 %0, %1, %2" : "=v"(r) : "v"(a), "v"(b));
    return r;
}

DEV bf16x8 ld_bf16x8(const unsigned short* p) { return *(const bf16x8*)p; }

// async global->LDS, 16B per lane; lds dest = wave-uniform base + lane*16
DEV void gl16(const unsigned short* g, unsigned short* l) {
    __builtin_amdgcn_global_load_lds(
        (const __attribute__((address_space(1))) u32*)g,
        (__attribute__((address_space(3))) u32*)l, 16, 0, 0);
}

// ---- prep (fused): blocks [0,4096) = x->bf16 ; [4096,8192) = W transposes ----
__global__ void prep(const float* __restrict__ x, unsigned short* __restrict__ xb,
                     const float* __restrict__ W0, const float* __restrict__ W1,
                     const float* __restrict__ W2, const float* __restrict__ W3,
                     unsigned short* __restrict__ WtBase) {
    __shared__ float tile[32][33];
    int blk = blockIdx.x;
    if (blk < 4096) {
        int i = blk * 256 + threadIdx.x;
        float4 v = ((const float4*)x)[i];
        uint2 o;
        o.x = pk2bf(v.x, v.y);
        o.y = pk2bf(v.z, v.w);
        ((uint2*)xb)[i] = o;
        return;
    }
    blk -= 4096;                 // 4 weights x 1024 tiles
    int wsel = blk >> 10;
    const float* W = (wsel == 0) ? W0 : (wsel == 1) ? W1 : (wsel == 2) ? W2 : W3;
    unsigned short* Wt = WtBase + (size_t)wsel * DD * DD;
    int t = blk & 1023;
    int n0 = (t & 31) * 32, k0 = (t >> 5) * 32;
    int tx = threadIdx.x & 31, ty = threadIdx.x >> 5; // 32 x 8
    #pragma unroll
    for (int i = 0; i < 4; ++i)
        tile[ty + 8 * i][tx] = W[(size_t)(k0 + ty + 8 * i) * DD + n0 + tx];
    __syncthreads();
    #pragma unroll
    for (int i = 0; i < 4; ++i)
        Wt[(size_t)(n0 + ty + 8 * i) * DD + k0 + tx] = f2bf(tile[tx][ty + 8 * i]);
}

// ====================== QKV GEMM v7: z-merged 128x128, 3-buffer counted vmcnt ======================
// (R8 version, unchanged: A-frags shared across the 3 products -> 10 ds_reads / 24 MFMA.)
__global__ __launch_bounds__(512, 2) void qkv_gemm(
    const unsigned short* __restrict__ xb,
    const unsigned short* __restrict__ WtBase,
    const float* __restrict__ bq, const float* __restrict__ bk, const float* __restrict__ bv,
    unsigned short* __restrict__ Qb, unsigned short* __restrict__ Kb, unsigned short* __restrict__ Vt)
{
    __shared__ __align__(16) unsigned short AL[3][128 * 32];     // 24 KB
    __shared__ __align__(16) unsigned short BL[3][3][128 * 32];  // 72 KB

    // XCD-balanced remap (R4-proven): xcd k <- xe in [4(k&1),+4), ye in [8(k>>1),+8)
    const int gid2 = blockIdx.x + 8 * blockIdx.y;   // 0..255; xcd = gid2&7
    const int xk = gid2 & 7, o = gid2 >> 3;
    const int xe = (xk & 1) * 4 + (o & 3);
    const int ye = (xk >> 1) * 8 + (o >> 2);
    const int m0g = ye * 128;
    const int n0g = xe * 128;

    const int wave = threadIdx.x >> 6, lane = threadIdx.x & 63;
    const int quad = lane >> 4, lcol = lane & 15;
    const int wr = wave >> 2, wc = wave & 3;   // 2M x 4N wave grid; per-wave 64x32 per z

    f32x4 acc[3][4][2];
    #pragma unroll
    for (int z = 0; z < 3; ++z)
        #pragma unroll
        for (int i = 0; i < 4; ++i)
            #pragma unroll
            for (int j = 0; j < 2; ++j) acc[z][i][j] = (f32x4){0.f, 0.f, 0.f, 0.f};

    // stage one K-slice for A + all 3 B: 4 gl16 per thread (vmcnt unit = 4)
    auto stage = [&](int ks, int bf) {
        int bi = threadIdx.x;                 // segment 0..511
        int row = bi >> 2, p = (bi & 3) ^ ((row >> 1) & 3);
        gl16(xb + (size_t)(m0g + row) * DD + ks + p * 8, &AL[bf][wave * 512]);
        #pragma unroll
        for (int z = 0; z < 3; ++z)
            gl16(WtBase + (size_t)z * DD * DD + (size_t)(n0g + row) * DD + ks + p * 8,
                 &BL[bf][z][wave * 512]);
    };

    auto compute = [&](int bf) {
        bf16x8 af[4];
        #pragma unroll
        for (int mt = 0; mt < 4; ++mt) {
            int row = wr * 64 + mt * 16 + lcol;
            af[mt] = ld_bf16x8(&AL[bf][(row * 4 + (quad ^ ((row >> 1) & 3))) * 8]);
        }
        #pragma unroll
        for (int z = 0; z < 3; ++z) {
            bf16x8 bz[2];
            #pragma unroll
            for (int nt = 0; nt < 2; ++nt) {
                int row = wc * 32 + nt * 16 + lcol;
                bz[nt] = ld_bf16x8(&BL[bf][z][(row * 4 + (quad ^ ((row >> 1) & 3))) * 8]);
            }
            if (z < 2) { // transposed product: D[row=out_n][col=token]
                #pragma unroll
                for (int mt = 0; mt < 4; ++mt)
                    #pragma unroll
                    for (int nt = 0; nt < 2; ++nt)
                        acc[z][mt][nt] = __builtin_amdgcn_mfma_f32_16x16x32_bf16(bz[nt], af[mt], acc[z][mt][nt], 0, 0, 0);
            } else {
                #pragma unroll
                for (int mt = 0; mt < 4; ++mt)
                    #pragma unroll
                    for (int nt = 0; nt < 2; ++nt)
                        acc[z][mt][nt] = __builtin_amdgcn_mfma_f32_16x16x32_bf16(af[mt], bz[nt], acc[z][mt][nt], 0, 0, 0);
            }
        }
    };

    stage(0, 0);
    stage(32, 1);

    // main loop: k = 0..29, buffers (k%3); vmcnt(8) = 2 stages (8 gl16) in flight
    for (int kk = 0; kk < 30; kk += 3) {
        #pragma unroll
        for (int u = 0; u < 3; ++u) {
            int k = kk + u;
            stage((k + 2) * 32, (u + 2) % 3);
            asm volatile("s_waitcnt vmcnt(8)" ::: "memory");
            __builtin_amdgcn_s_barrier();
            __builtin_amdgcn_sched_barrier(0);
            compute(u);
            __builtin_amdgcn_s_barrier();
        }
    }
    // k = 30 (buf 0): only stage(31) in flight
    asm volatile("s_waitcnt vmcnt(4)" ::: "memory");
    __builtin_amdgcn_s_barrier();
    __builtin_amdgcn_sched_barrier(0);
    compute(0);
    __builtin_amdgcn_s_barrier();
    // k = 31 (buf 1): drain
    asm volatile("s_waitcnt vmcnt(0)" ::: "memory");
    __builtin_amdgcn_s_barrier();
    __builtin_amdgcn_sched_barrier(0);
    compute(1);

    // ---- epilogue: same store math as R5, per-wave ranges 64x32 ----
    #pragma unroll
    for (int z = 0; z < 2; ++z) {
        unsigned short* dst = (z == 0) ? Qb : Kb;
        const float sc = (z == 0) ? QSC : 1.0f;
        const float* bias = (z == 0) ? bq : bk;
        #pragma unroll
        for (int mt = 0; mt < 4; ++mt) {
            int m = m0g + wr * 64 + mt * 16 + lcol;        // token -> (b,s)
            int b_ = m >> 11, s = m & (SS - 1);
            #pragma unroll
            for (int nt = 0; nt < 2; ++nt) {
                int nbt = n0g + wc * 32 + nt * 16 + quad * 4;  // 4 consecutive out_n
                int h = nbt >> 6, dh0 = nbt & 63;
                float4 bv4 = *(const float4*)&bias[nbt];
                uint2 o2;
                o2.x = pk2bf((acc[z][mt][nt][0] + bv4.x) * sc, (acc[z][mt][nt][1] + bv4.y) * sc);
                o2.y = pk2bf((acc[z][mt][nt][2] + bv4.z) * sc, (acc[z][mt][nt][3] + bv4.w) * sc);
                *(uint2*)&dst[(((size_t)b_ * HH + h) * SS + s) * DHD + dh0] = o2;
            }
        }
    }
    #pragma unroll
    for (int mt = 0; mt < 4; ++mt) {
        int mbt = m0g + wr * 64 + mt * 16 + quad * 4;      // 4 consecutive tokens
        int b_ = mbt >> 11, s0 = mbt & (SS - 1);
        #pragma unroll
        for (int nt = 0; nt < 2; ++nt) {
            int n = n0g + wc * 32 + nt * 16 + lcol;        // out_n
            int h = n >> 6, dh = n & 63;
            float bvv = bv[n];
            uint2 o2;
            o2.x = pk2bf(acc[2][mt][nt][0] + bvv, acc[2][mt][nt][1] + bvv);
            o2.y = pk2bf(acc[2][mt][nt][2] + bvv, acc[2][mt][nt][3] + bvv);
            *(uint2*)&Vt[(((size_t)b_ * HH + h) * DHD + dh) * SS + s0] = o2;
        }
    }
}

// ====================== attention v11: key-split wave pairs on the v10 substrate ======================
// R8 model: v10 is DS-read-throughput-bound (16 waves x 16 ds_read_b128 x 12cyc =
// ~98K cyc/CU vs 112.5K wall, 87%). v11 halves DS reads at constant MFMA: wave =
// (qg, kh) = 4 q-groups x 32 rows x 2 key-halves (32 of 64 chunk keys). QK: 4 K-reads
// (shared by both 16-row sub-groups) : 8 MFMA; PV: 4 V-reads : 8 MFMA. Same grid 512,
// same 16 waves/CU (unlike R0-v8's occupancy loss). v10's K-row permutation +
// in-register P trick carry over per sub-group with kf2 = kh. Block-uniform m0
// (v9-proven), epilogue kh-pair combine via conflict-free LDS exchange (K/V dead).
__global__ __launch_bounds__(512, 4) void attn(
    const unsigned short* __restrict__ Qb,
    const unsigned short* __restrict__ Kb,
    const unsigned short* __restrict__ Vt,
    unsigned short* __restrict__ Ob)
{
    __shared__ __align__(16) unsigned short Kld[2][64 * 64]; // keys x dh, swz(r)-swizzled blocks
    __shared__ __align__(16) unsigned short Vld[2][64 * 64]; // dh x keys, (dh&7)-swizzled blocks
    __shared__ float exch[8 * 16 * 64];                      // 32 KB epilogue exchange
    __shared__ float psx[8][2][16];
    __shared__ float smax[8];

    const int g = blockIdx.y * gridDim.x + blockIdx.x;  // grid (16, 32) = 512
    const int bh = (g & 7) * 4 + ((g >> 3) & 3);        // fixed g%32 per bh -> fixed XCD
    const int qt = g >> 5;                               // 0..15
    const int b = bh >> 4, h = bh & (HH - 1);
    const unsigned short* Qbh = Qb + (size_t)bh * SS * DHD;
    const unsigned short* Kbh = Kb + (size_t)bh * SS * DHD;
    const unsigned short* Vbh = Vt + (size_t)bh * DHD * SS;

    const int wave = threadIdx.x >> 6, lane = threadIdx.x & 63;
    const int quad = lane >> 4, lcol = lane & 15;
    const int qg = wave >> 1, kh = wave & 1;
    const int rowbase = qt * 128 + qg * 32;

    // Q B-frags for the wave's 2 sub-groups of 16 rows (0.125*log2e folded into Q)
    bf16x8 qf0[2], qf1[2];
    #pragma unroll
    for (int g2 = 0; g2 < 2; ++g2) {
        qf0[g2] = ld_bf16x8(Qbh + (size_t)(rowbase + g2 * 16 + lcol) * DHD + quad * 8);
        qf1[g2] = ld_bf16x8(Qbh + (size_t)(rowbase + g2 * 16 + lcol) * DHD + 32 + quad * 8);
    }

    // K-row this lane reads for QK MFMA-pair j (kf2 = kh fixed): keys 8q+4j+r -> regs
    auto krow = [&](int j) {
        return kh * 32 + ((lcol >> 2) << 3) + j * 4 + (lcol & 3);
    };
    auto kswz = [](int r) { return (r & 3) | (((r >> 3) & 1) << 2); };

    auto stage = [&](int c, int bf) {
        int kb = c * 64;
        #pragma unroll
        for (int i = 0; i < 2; ++i) {
            int j = wave * 2 + i;
            if (j < 8) { // K: rows = keys, 8 parts of dh, swz(r) slot permutation
                int bi = j * 64 + lane;
                int r = bi >> 3, p = (bi & 7) ^ ((r & 3) | (((r >> 3) & 1) << 2));
                gl16(Kbh + (size_t)(kb + r) * DHD + p * 8, &Kld[bf][j * 512]);
            } else {     // V: rows = dh, 8 parts of keys
                int jj = j - 8;
                int bi = jj * 64 + lane;
                int dh = bi >> 3, p = (bi & 7) ^ (dh & 7);
                gl16(Vbh + (size_t)dh * SS + kb + p * 8, &Vld[bf][jj * 512]);
            }
        }
    };

    // ---- prologue: stage chunk 0, block-uniform m0 estimate ----
    stage(0, 0);
    __syncthreads();
    {
        float m0 = -1e30f;
        #pragma unroll
        for (int j = 0; j < 2; ++j) {
            int kr = krow(j), sw = kswz(kr);
            bf16x8 ka0 = ld_bf16x8(&Kld[0][(kr * 8 + (quad ^ sw)) * 8]);
            bf16x8 ka1 = ld_bf16x8(&Kld[0][(kr * 8 + ((quad + 4) ^ sw)) * 8]);
            #pragma unroll
            for (int g2 = 0; g2 < 2; ++g2) {
                f32x4 s = (f32x4){0.f, 0.f, 0.f, 0.f};
                s = __builtin_amdgcn_mfma_f32_16x16x32_bf16(ka0, qf0[g2], s, 0, 0, 0);
                s = __builtin_amdgcn_mfma_f32_16x16x32_bf16(ka1, qf1[g2], s, 0, 0, 0);
                #pragma unroll
                for (int r = 0; r < 4; ++r) m0 = fmaxf(m0, s[r]);
            }
        }
        #pragma unroll
        for (int msk = 1; msk < 64; msk <<= 1) m0 = fmaxf(m0, __shfl_xor(m0, msk, 64));
        if (lane == 0) smax[wave] = m0;
    }
    __syncthreads();
    float m0b = smax[0];
    #pragma unroll
    for (int w2 = 1; w2 < 8; ++w2) m0b = fmaxf(m0b, smax[w2]);
    const f32x4 minit = (f32x4){-m0b, -m0b, -m0b, -m0b};

    // ---- main loop over 32 chunks of 64 keys (wave owns 32-key half kh) ----
    f32x4 oacc[2][4];
    #pragma unroll
    for (int g2 = 0; g2 < 2; ++g2)
        #pragma unroll
        for (int nt = 0; nt < 4; ++nt) oacc[g2][nt] = (f32x4){0.f, 0.f, 0.f, 0.f};
    float ps0 = 0.f, ps1 = 0.f;

    for (int c = 0; c < 32; ++c) {
        int bf = c & 1;
        if (c + 1 < 32) stage(c + 1, (c + 1) & 1);

        // 4 K-reads shared across both sub-groups
        bf16x8 ka0[2], ka1[2];
        #pragma unroll
        for (int j = 0; j < 2; ++j) {
            int kr = krow(j), sw = kswz(kr);
            ka0[j] = ld_bf16x8(&Kld[bf][(kr * 8 + (quad ^ sw)) * 8]);
            ka1[j] = ld_bf16x8(&Kld[bf][(kr * 8 + ((quad + 4) ^ sw)) * 8]);
        }
        // QK + exp2 + in-register P pack, per sub-group
        bf16x8 paf[2];
        #pragma unroll
        for (int g2 = 0; g2 < 2; ++g2) {
            u32 w[4];
            #pragma unroll
            for (int j = 0; j < 2; ++j) {
                f32x4 s = minit;
                s = __builtin_amdgcn_mfma_f32_16x16x32_bf16(ka0[j], qf0[g2], s, 0, 0, 0);
                s = __builtin_amdgcn_mfma_f32_16x16x32_bf16(ka1[j], qf1[g2], s, 0, 0, 0);
                float e0 = EXP2(s[0]), e1 = EXP2(s[1]);
                float e2 = EXP2(s[2]), e3 = EXP2(s[3]);
                if (g2 == 0) ps0 += (e0 + e1) + (e2 + e3);
                else         ps1 += (e0 + e1) + (e2 + e3);
                w[j * 2]     = cvtpk2bf(e0, e1);
                w[j * 2 + 1] = cvtpk2bf(e2, e3);
            }
            union { u32x4 u; bf16x8 v; } pu;
            pu.u = (u32x4){w[0], w[1], w[2], w[3]};
            paf[g2] = pu.v;
        }

        // PV: 4 V-reads (kf2 = kh) shared across both sub-groups
        #pragma unroll
        for (int nt = 0; nt < 4; ++nt) {
            int dh = nt * 16 + lcol;
            bf16x8 vb = ld_bf16x8(&Vld[bf][(dh * 8 + ((kh * 4 + quad) ^ (dh & 7))) * 8]);
            oacc[0][nt] = __builtin_amdgcn_mfma_f32_16x16x32_bf16(paf[0], vb, oacc[0][nt], 0, 0, 0);
            oacc[1][nt] = __builtin_amdgcn_mfma_f32_16x16x32_bf16(paf[1], vb, oacc[1][nt], 0, 0, 0);
        }
        __syncthreads();
    }

    // ---- epilogue: kh-pair combine + normalize ----
    // row-sum totals per q-row (valid for q-row = lcol after quad reduction)
    ps0 += __shfl_xor(ps0, 16, 64); ps0 += __shfl_xor(ps0, 32, 64);
    ps1 += __shfl_xor(ps1, 16, 64); ps1 += __shfl_xor(ps1, 32, 64);
    if (lane < 16) { psx[wave][0][lane] = ps0; psx[wave][1][lane] = ps1; }
    // write the dh-half the partner keeps (nt = (kh^1)*2 + t); lane-contiguous, conflict-free
    #pragma unroll
    for (int g2 = 0; g2 < 2; ++g2)
        #pragma unroll
        for (int t = 0; t < 2; ++t)
            #pragma unroll
            for (int r = 0; r < 4; ++r)
                exch[((wave * 16) + g2 * 8 + t * 4 + r) * 64 + lane] = oacc[g2][(kh ^ 1) * 2 + t][r];
    __syncthreads();
    const int pw = wave ^ 1;
    #pragma unroll
    for (int g2 = 0; g2 < 2; ++g2) {
        #pragma unroll
        for (int r = 0; r < 4; ++r) {
            int q = quad * 4 + r;
            float pstot = psx[qg * 2][g2][q] + psx[qg * 2 + 1][g2][q];
            float iv = 1.0f / pstot;
            int srow = rowbase + g2 * 16 + q;
            size_t base = (((size_t)b * SS + srow) * HH + h) * DHD;
            #pragma unroll
            for (int t = 0; t < 2; ++t) {
                int nt = kh * 2 + t;
                float v = oacc[g2][nt][r] + exch[((pw * 16) + g2 * 8 + t * 4 + r) * 64 + lane];
                Ob[base + nt * 16 + lcol] = f2bf(v * iv);
            }
        }
    }
}

// ====================== output GEMM v2 ======================
// Tile 64 tokens x 128 out_n, BK=64 dbuf (16 barriers), transposed product:
// A = Wto (rows = out_n), B = Ob (rows = tokens) -> D[m=out_n][n=token];
// reg-quad r gives 4 consecutive out_n -> float4 stores (8 per thread).
// LDS frag swizzle = attn Kld 8-part scheme (measured 0 conflicts).
__global__ __launch_bounds__(256) void out_gemm(
    const unsigned short* __restrict__ Ob,
    const unsigned short* __restrict__ Wto,
    const float* __restrict__ bo,
    float* __restrict__ out)
{
    __shared__ __align__(16) unsigned short Wld[2][128 * 64]; // out_n x k
    __shared__ __align__(16) unsigned short Old[2][64 * 64];  // token x k

    const int m0g = blockIdx.y * 64;    // tokens
    const int n0g = blockIdx.x * 128;   // out_n
    const int wave = threadIdx.x >> 6, lane = threadIdx.x & 63;
    const int quad = lane >> 4, lcol = lane & 15;
    const int nb = wave * 32;           // wave's out_n sub-range

    f32x4 acc[2][4];
    #pragma unroll
    for (int i = 0; i < 2; ++i)
        #pragma unroll
        for (int j = 0; j < 4; ++j) acc[i][j] = (f32x4){0.f, 0.f, 0.f, 0.f};

    auto stage = [&](int ks, int bf) {
        #pragma unroll
        for (int i = 0; i < 6; ++i) {
            int j = wave * 6 + i;
            if (j < 16) { // W: 128 rows x 8 parts
                int bi = j * 64 + lane;
                int r = bi >> 3, p = (bi & 7) ^ (r & 7);
                gl16(Wto + (size_t)(n0g + r) * DD + ks + p * 8, &Wld[bf][j * 512]);
            } else {      // Ob: 64 rows x 8 parts
                int jj = j - 16;
                int bi = jj * 64 + lane;
                int r = bi >> 3, p = (bi & 7) ^ (r & 7);
                gl16(Ob + (size_t)(m0g + r) * DD + ks + p * 8, &Old[bf][jj * 512]);
            }
        }
    };

    stage(0, 0);
    __syncthreads();

    for (int kk = 0; kk < 16; ++kk) {
        int bf = kk & 1;
        if (kk + 1 < 16) stage((kk + 1) * 64, (kk + 1) & 1);
        #pragma unroll
        for (int kh = 0; kh < 2; ++kh) {
            bf16x8 wf[2], of[4];
            #pragma unroll
            for (int i = 0; i < 2; ++i) {
                int row = nb + i * 16 + lcol;
                wf[i] = ld_bf16x8(&Wld[bf][(row * 8 + ((kh * 4 + quad) ^ (row & 7))) * 8]);
            }
            #pragma unroll
            for (int j = 0; j < 4; ++j) {
                int row = j * 16 + lcol;
                of[j] = ld_bf16x8(&Old[bf][(row * 8 + ((kh * 4 + quad) ^ (row & 7))) * 8]);
            }
            #pragma unroll
            for (int i = 0; i < 2; ++i)
                #pragma unroll
                for (int j = 0; j < 4; ++j)
                    acc[i][j] = __builtin_amdgcn_mfma_f32_16x16x32_bf16(wf[i], of[j], acc[i][j], 0, 0, 0);
        }
        __syncthreads();
    }

    // C: col = token (lcol within j-tile), row = out_n (quad*4 + r, consecutive)
    #pragma unroll
    for (int i = 0; i < 2; ++i) {
        int n4 = n0g + nb + i * 16 + quad * 4;
        float4 bv4 = *(const float4*)&bo[n4];
        #pragma unroll
        for (int j = 0; j < 4; ++j) {
            int token = m0g + j * 16 + lcol;
            float4 o;
            o.x = acc[i][j][0] + bv4.x;
            o.y = acc[i][j][1] + bv4.y;
            o.z = acc[i][j][2] + bv4.z;
            o.w = acc[i][j][3] + bv4.w;
            *(float4*)&out[(size_t)token * DD + n4] = o;
        }
    }
}

extern "C" void kernel_launch(void* const* d_in, const int* in_sizes, int n_in,
                              void* d_out, int out_size, void* d_ws, size_t ws_size,
                              hipStream_t stream)
{
    const float* x  = (const float*)d_in[0];
    const float* Wq = (const float*)d_in[1];
    const float* bq = (const float*)d_in[2];
    const float* Wk = (const float*)d_in[3];
    const float* bk = (const float*)d_in[4];
    const float* Wv = (const float*)d_in[5];
    const float* bv = (const float*)d_in[6];
    const float* Wo = (const float*)d_in[7];
    const float* bo = (const float*)d_in[8];
    float* out = (float*)d_out;

    unsigned short* ws = (unsigned short*)d_ws;
    unsigned short* Wt  = ws;                        // 4 * D*D (q,k,v,o)
    unsigned short* Wto = Wt + 3 * (size_t)DD * DD;
    unsigned short* Qb  = Wt + 4 * (size_t)DD * DD;  // M*D each
    unsigned short* Kb  = Qb + (size_t)MM * DD;
    unsigned short* Vt  = Kb + (size_t)MM * DD;
    unsigned short* xb  = Vt + (size_t)MM * DD;      // total 40 MB
    unsigned short* Ob  = xb;                        // alias: xb dead after qkv_gemm

    prep<<<8192, 256, 0, stream>>>(x, xb, Wq, Wk, Wv, Wo, Wt);

    qkv_gemm<<<dim3(8, 32), 512, 0, stream>>>(xb, Wt, bq, bk, bv, Qb, Kb, Vt);

    attn<<<dim3(16, 32), 512, 0, stream>>>(Qb, Kb, Vt, Ob);

    out_gemm<<<dim3(DD / 128, MM / 64), 256, 0, stream>>>(Ob, Wto, bo, out);
}

// Round 10
// 183.423 us; speedup vs baseline: 1.0799x; 1.0799x over previous
//
#include <hip/hip_runtime.h>
#include <hip/hip_bf16.h>

#define DEV __device__ __forceinline__

typedef short bf16x8 __attribute__((ext_vector_type(8)));
typedef float f32x4 __attribute__((ext_vector_type(4)));
typedef unsigned int u32;
typedef unsigned int u32x4 __attribute__((ext_vector_type(4)));

constexpr int BB = 2, SS = 2048, DD = 1024, HH = 16, DHD = 64;
constexpr int MM = BB * SS; // 4096
#define QSC 0.1803368801111f  /* 0.125 * log2(e): scores in log2 domain */

#if __has_builtin(__builtin_amdgcn_exp2f)
#define EXP2(x) __builtin_amdgcn_exp2f(x)
#else
#define EXP2(x) exp2f(x)
#endif

// round-half-up bf16; bias only at exact-half cases
DEV unsigned short f2bf(float f) {
    union { float f; unsigned int u; } v; v.f = f;
    return (unsigned short)((v.u + 0x8000u) >> 16);
}
// pack two f32 -> (bf16(b)<<16)|bf16(a) : add, add, v_perm = 3 instr
#if __has_builtin(__builtin_amdgcn_perm)
DEV u32 pk2bf(float a, float b) {
    union { float f; u32 u; } ua, ub; ua.f = a; ub.f = b;
    return __builtin_amdgcn_perm(ub.u + 0x8000u, ua.u + 0x8000u, 0x07060302u);
}
#else
DEV u32 pk2bf(float a, float b) {
    union { float f; u32 u; } ua, ub; ua.f = a; ub.f = b;
    return ((ua.u + 0x8000u) >> 16) | ((ub.u + 0x8000u) & 0xffff0000u);
}
#endif

// single-instruction RNE pack (gfx950 has no builtin; inline asm per T12)
DEV u32 cvtpk2bf(float a, float b) {
    u32 r;
    asm("v_cvt_pk_bf16_f32 %0, %1, %2" : "=v"(r) : "v"(a), "v"(b));
    return r;
}

DEV bf16x8 ld_bf16x8(const unsigned short* p) { return *(const bf16x8*)p; }

// async global->LDS, 16B per lane; lds dest = wave-uniform base + lane*16
DEV void gl16(const unsigned short* g, unsigned short* l) {
    __builtin_amdgcn_global_load_lds(
        (const __attribute__((address_space(1))) u32*)g,
        (__attribute__((address_space(3))) u32*)l, 16, 0, 0);
}

// ---- prep (fused): blocks [0,4096) = x->bf16 ; [4096,8192) = W transposes ----
__global__ void prep(const float* __restrict__ x, unsigned short* __restrict__ xb,
                     const float* __restrict__ W0, const float* __restrict__ W1,
                     const float* __restrict__ W2, const float* __restrict__ W3,
                     unsigned short* __restrict__ WtBase) {
    __shared__ float tile[32][33];
    int blk = blockIdx.x;
    if (blk < 4096) {
        int i = blk * 256 + threadIdx.x;
        float4 v = ((const float4*)x)[i];
        uint2 o;
        o.x = pk2bf(v.x, v.y);
        o.y = pk2bf(v.z, v.w);
        ((uint2*)xb)[i] = o;
        return;
    }
    blk -= 4096;                 // 4 weights x 1024 tiles
    int wsel = blk >> 10;
    const float* W = (wsel == 0) ? W0 : (wsel == 1) ? W1 : (wsel == 2) ? W2 : W3;
    unsigned short* Wt = WtBase + (size_t)wsel * DD * DD;
    int t = blk & 1023;
    int n0 = (t & 31) * 32, k0 = (t >> 5) * 32;
    int tx = threadIdx.x & 31, ty = threadIdx.x >> 5; // 32 x 8
    #pragma unroll
    for (int i = 0; i < 4; ++i)
        tile[ty + 8 * i][tx] = W[(size_t)(k0 + ty + 8 * i) * DD + n0 + tx];
    __syncthreads();
    #pragma unroll
    for (int i = 0; i < 4; ++i)
        Wt[(size_t)(n0 + ty + 8 * i) * DD + k0 + tx] = f2bf(tile[tx][ty + 8 * i]);
}

// ====================== QKV GEMM v7: z-merged 128x128, 3-buffer counted vmcnt ======================
// (R8 version, unchanged: A-frags shared across the 3 products -> 10 ds_reads / 24 MFMA.)
__global__ __launch_bounds__(512, 2) void qkv_gemm(
    const unsigned short* __restrict__ xb,
    const unsigned short* __restrict__ WtBase,
    const float* __restrict__ bq, const float* __restrict__ bk, const float* __restrict__ bv,
    unsigned short* __restrict__ Qb, unsigned short* __restrict__ Kb, unsigned short* __restrict__ Vt)
{
    __shared__ __align__(16) unsigned short AL[3][128 * 32];     // 24 KB
    __shared__ __align__(16) unsigned short BL[3][3][128 * 32];  // 72 KB

    // XCD-balanced remap (R4-proven): xcd k <- xe in [4(k&1),+4), ye in [8(k>>1),+8)
    const int gid2 = blockIdx.x + 8 * blockIdx.y;   // 0..255; xcd = gid2&7
    const int xk = gid2 & 7, o = gid2 >> 3;
    const int xe = (xk & 1) * 4 + (o & 3);
    const int ye = (xk >> 1) * 8 + (o >> 2);
    const int m0g = ye * 128;
    const int n0g = xe * 128;

    const int wave = threadIdx.x >> 6, lane = threadIdx.x & 63;
    const int quad = lane >> 4, lcol = lane & 15;
    const int wr = wave >> 2, wc = wave & 3;   // 2M x 4N wave grid; per-wave 64x32 per z

    f32x4 acc[3][4][2];
    #pragma unroll
    for (int z = 0; z < 3; ++z)
        #pragma unroll
        for (int i = 0; i < 4; ++i)
            #pragma unroll
            for (int j = 0; j < 2; ++j) acc[z][i][j] = (f32x4){0.f, 0.f, 0.f, 0.f};

    // stage one K-slice for A + all 3 B: 4 gl16 per thread (vmcnt unit = 4)
    auto stage = [&](int ks, int bf) {
        int bi = threadIdx.x;                 // segment 0..511
        int row = bi >> 2, p = (bi & 3) ^ ((row >> 1) & 3);
        gl16(xb + (size_t)(m0g + row) * DD + ks + p * 8, &AL[bf][wave * 512]);
        #pragma unroll
        for (int z = 0; z < 3; ++z)
            gl16(WtBase + (size_t)z * DD * DD + (size_t)(n0g + row) * DD + ks + p * 8,
                 &BL[bf][z][wave * 512]);
    };

    auto compute = [&](int bf) {
        bf16x8 af[4];
        #pragma unroll
        for (int mt = 0; mt < 4; ++mt) {
            int row = wr * 64 + mt * 16 + lcol;
            af[mt] = ld_bf16x8(&AL[bf][(row * 4 + (quad ^ ((row >> 1) & 3))) * 8]);
        }
        #pragma unroll
        for (int z = 0; z < 3; ++z) {
            bf16x8 bz[2];
            #pragma unroll
            for (int nt = 0; nt < 2; ++nt) {
                int row = wc * 32 + nt * 16 + lcol;
                bz[nt] = ld_bf16x8(&BL[bf][z][(row * 4 + (quad ^ ((row >> 1) & 3))) * 8]);
            }
            if (z < 2) { // transposed product: D[row=out_n][col=token]
                #pragma unroll
                for (int mt = 0; mt < 4; ++mt)
                    #pragma unroll
                    for (int nt = 0; nt < 2; ++nt)
                        acc[z][mt][nt] = __builtin_amdgcn_mfma_f32_16x16x32_bf16(bz[nt], af[mt], acc[z][mt][nt], 0, 0, 0);
            } else {
                #pragma unroll
                for (int mt = 0; mt < 4; ++mt)
                    #pragma unroll
                    for (int nt = 0; nt < 2; ++nt)
                        acc[z][mt][nt] = __builtin_amdgcn_mfma_f32_16x16x32_bf16(af[mt], bz[nt], acc[z][mt][nt], 0, 0, 0);
            }
        }
    };

    stage(0, 0);
    stage(32, 1);

    // main loop: k = 0..29, buffers (k%3); vmcnt(8) = 2 stages (8 gl16) in flight
    for (int kk = 0; kk < 30; kk += 3) {
        #pragma unroll
        for (int u = 0; u < 3; ++u) {
            int k = kk + u;
            stage((k + 2) * 32, (u + 2) % 3);
            asm volatile("s_waitcnt vmcnt(8)" ::: "memory");
            __builtin_amdgcn_s_barrier();
            __builtin_amdgcn_sched_barrier(0);
            compute(u);
            __builtin_amdgcn_s_barrier();
        }
    }
    // k = 30 (buf 0): only stage(31) in flight
    asm volatile("s_waitcnt vmcnt(4)" ::: "memory");
    __builtin_amdgcn_s_barrier();
    __builtin_amdgcn_sched_barrier(0);
    compute(0);
    __builtin_amdgcn_s_barrier();
    // k = 31 (buf 1): drain
    asm volatile("s_waitcnt vmcnt(0)" ::: "memory");
    __builtin_amdgcn_s_barrier();
    __builtin_amdgcn_sched_barrier(0);
    compute(1);

    // ---- epilogue: same store math as R5, per-wave ranges 64x32 ----
    #pragma unroll
    for (int z = 0; z < 2; ++z) {
        unsigned short* dst = (z == 0) ? Qb : Kb;
        const float sc = (z == 0) ? QSC : 1.0f;
        const float* bias = (z == 0) ? bq : bk;
        #pragma unroll
        for (int mt = 0; mt < 4; ++mt) {
            int m = m0g + wr * 64 + mt * 16 + lcol;        // token -> (b,s)
            int b_ = m >> 11, s = m & (SS - 1);
            #pragma unroll
            for (int nt = 0; nt < 2; ++nt) {
                int nbt = n0g + wc * 32 + nt * 16 + quad * 4;  // 4 consecutive out_n
                int h = nbt >> 6, dh0 = nbt & 63;
                float4 bv4 = *(const float4*)&bias[nbt];
                uint2 o2;
                o2.x = pk2bf((acc[z][mt][nt][0] + bv4.x) * sc, (acc[z][mt][nt][1] + bv4.y) * sc);
                o2.y = pk2bf((acc[z][mt][nt][2] + bv4.z) * sc, (acc[z][mt][nt][3] + bv4.w) * sc);
                *(uint2*)&dst[(((size_t)b_ * HH + h) * SS + s) * DHD + dh0] = o2;
            }
        }
    }
    #pragma unroll
    for (int mt = 0; mt < 4; ++mt) {
        int mbt = m0g + wr * 64 + mt * 16 + quad * 4;      // 4 consecutive tokens
        int b_ = mbt >> 11, s0 = mbt & (SS - 1);
        #pragma unroll
        for (int nt = 0; nt < 2; ++nt) {
            int n = n0g + wc * 32 + nt * 16 + lcol;        // out_n
            int h = n >> 6, dh = n & 63;
            float bvv = bv[n];
            uint2 o2;
            o2.x = pk2bf(acc[2][mt][nt][0] + bvv, acc[2][mt][nt][1] + bvv);
            o2.y = pk2bf(acc[2][mt][nt][2] + bvv, acc[2][mt][nt][3] + bvv);
            *(uint2*)&Vt[(((size_t)b_ * HH + h) * DHD + dh) * SS + s0] = o2;
        }
    }
}

// ====================== attention v10 (reverted; measured 46.9 us in R8) ======================
// v7 + P-in-register: QK loads K-rows in permuted order kr = kf2*32 + 8*(lcol>>2)
// + 4*j + (lcol&3) so S-output regs concatenate into the PV A-fragment directly
// (2x v_cvt_pk_bf16_f32 each); tb LDS round-trip deleted. v11's shared-fragment
// variant regressed (VALU chain lengthened) — keep chains short.
__global__ __launch_bounds__(512, 4) void attn(
    const unsigned short* __restrict__ Qb,
    const unsigned short* __restrict__ Kb,
    const unsigned short* __restrict__ Vt,
    unsigned short* __restrict__ Ob)
{
    __shared__ __align__(16) unsigned short Kld[2][64 * 64]; // keys x dh, swz(r)-swizzled blocks
    __shared__ __align__(16) unsigned short Vld[2][64 * 64]; // dh x keys, (dh&7)-swizzled blocks

    const int g = blockIdx.y * gridDim.x + blockIdx.x;  // grid (16, 32) = 512
    const int bh = (g & 7) * 4 + ((g >> 3) & 3);        // fixed g%32 per bh -> fixed XCD
    const int qt = g >> 5;                               // 0..15
    const int b = bh >> 4, h = bh & (HH - 1);
    const unsigned short* Qbh = Qb + (size_t)bh * SS * DHD;
    const unsigned short* Kbh = Kb + (size_t)bh * SS * DHD;
    const unsigned short* Vbh = Vt + (size_t)bh * DHD * SS;

    const int wave = threadIdx.x >> 6, lane = threadIdx.x & 63;
    const int quad = lane >> 4, lcol = lane & 15;
    const int rowbase = qt * 128 + wave * 16;

    // Q B-frags (n = q-row, k = dh); 0.125*log2e folded into Q
    bf16x8 qf0 = ld_bf16x8(Qbh + (size_t)(rowbase + lcol) * DHD + quad * 8);
    bf16x8 qf1 = ld_bf16x8(Qbh + (size_t)(rowbase + lcol) * DHD + 32 + quad * 8);

    // K-row this lane reads for QK MFMA-pair (kf2, j): keys 8q+4j+r land in regs
    auto krow = [&](int kf2, int j) {
        return kf2 * 32 + ((lcol >> 2) << 3) + j * 4 + (lcol & 3);
    };
    auto kswz = [](int r) { return (r & 3) | (((r >> 3) & 1) << 2); };

    auto stage = [&](int c, int bf) {
        int kb = c * 64;
        #pragma unroll
        for (int i = 0; i < 2; ++i) {
            int j = wave * 2 + i;
            if (j < 8) { // K: rows = keys, 8 parts of dh, swz(r) slot permutation
                int bi = j * 64 + lane;
                int r = bi >> 3, p = (bi & 7) ^ ((r & 3) | (((r >> 3) & 1) << 2));
                gl16(Kbh + (size_t)(kb + r) * DHD + p * 8, &Kld[bf][j * 512]);
            } else {     // V: rows = dh, 8 parts of keys
                int jj = j - 8;
                int bi = jj * 64 + lane;
                int dh = bi >> 3, p = (bi & 7) ^ (dh & 7);
                gl16(Vbh + (size_t)dh * SS + kb + p * 8, &Vld[bf][jj * 512]);
            }
        }
    };

    // ---- prologue: stage chunk 0, wave-uniform m0 estimate from it ----
    stage(0, 0);
    __syncthreads();

    float m0 = -1e30f;
    #pragma unroll
    for (int kf2 = 0; kf2 < 2; ++kf2)
        #pragma unroll
        for (int j = 0; j < 2; ++j) {
            int kr = krow(kf2, j), sw = kswz(kr);
            bf16x8 ka0 = ld_bf16x8(&Kld[0][(kr * 8 + (quad ^ sw)) * 8]);
            bf16x8 ka1 = ld_bf16x8(&Kld[0][(kr * 8 + ((quad + 4) ^ sw)) * 8]);
            f32x4 s = (f32x4){0.f, 0.f, 0.f, 0.f};
            s = __builtin_amdgcn_mfma_f32_16x16x32_bf16(ka0, qf0, s, 0, 0, 0);
            s = __builtin_amdgcn_mfma_f32_16x16x32_bf16(ka1, qf1, s, 0, 0, 0);
            #pragma unroll
            for (int r = 0; r < 4; ++r) m0 = fmaxf(m0, s[r]);
        }
    #pragma unroll
    for (int msk = 1; msk < 64; msk <<= 1) m0 = fmaxf(m0, __shfl_xor(m0, msk, 64));
    const f32x4 minit = (f32x4){-m0, -m0, -m0, -m0};

    // ---- main loop over 32 chunks of 64 keys ----
    f32x4 oacc[4];
    #pragma unroll
    for (int nt = 0; nt < 4; ++nt) oacc[nt] = (f32x4){0.f, 0.f, 0.f, 0.f};
    float ps = 0.f;

    for (int c = 0; c < 32; ++c) {
        int bf = c & 1;
        if (c + 1 < 32) stage(c + 1, (c + 1) & 1);

        // S^T = K.Q^T (C-init = -m0) -> exp2 -> pack into PV A-frags (registers)
        bf16x8 paf[2];
        #pragma unroll
        for (int kf2 = 0; kf2 < 2; ++kf2) {
            u32 w[4];
            #pragma unroll
            for (int j = 0; j < 2; ++j) {
                int kr = krow(kf2, j), sw = kswz(kr);
                bf16x8 ka0 = ld_bf16x8(&Kld[bf][(kr * 8 + (quad ^ sw)) * 8]);
                bf16x8 ka1 = ld_bf16x8(&Kld[bf][(kr * 8 + ((quad + 4) ^ sw)) * 8]);
                f32x4 s = minit;
                s = __builtin_amdgcn_mfma_f32_16x16x32_bf16(ka0, qf0, s, 0, 0, 0);
                s = __builtin_amdgcn_mfma_f32_16x16x32_bf16(ka1, qf1, s, 0, 0, 0);
                float e0 = EXP2(s[0]), e1 = EXP2(s[1]);
                float e2 = EXP2(s[2]), e3 = EXP2(s[3]);
                ps += (e0 + e1) + (e2 + e3);
                w[j * 2]     = cvtpk2bf(e0, e1);
                w[j * 2 + 1] = cvtpk2bf(e2, e3);
            }
            union { u32x4 u; bf16x8 v; } pu;
            pu.u = (u32x4){w[0], w[1], w[2], w[3]};
            paf[kf2] = pu.v;
        }

        // PV: A = P (registers), B = V (from Vld) — identical to v7 reads
        #pragma unroll
        for (int kf2 = 0; kf2 < 2; ++kf2) {
            #pragma unroll
            for (int nt = 0; nt < 4; ++nt) {
                int dh = nt * 16 + lcol;
                bf16x8 vb = ld_bf16x8(&Vld[bf][(dh * 8 + ((kf2 * 4 + quad) ^ (dh & 7))) * 8]);
                oacc[nt] = __builtin_amdgcn_mfma_f32_16x16x32_bf16(paf[kf2], vb, oacc[nt], 0, 0, 0);
            }
        }
        __syncthreads();
    }

    // ---- epilogue: per-row normalize (rows owned entirely by this wave) ----
    ps += __shfl_xor(ps, 16, 64);
    ps += __shfl_xor(ps, 32, 64);
    float inv = 1.0f / ps;   // valid at lanes where lcol == q-row
    #pragma unroll
    for (int r = 0; r < 4; ++r) {
        float iv = __shfl(inv, quad * 4 + r, 64);
        int srow = rowbase + quad * 4 + r;
        size_t base = (((size_t)b * SS + srow) * HH + h) * DHD;
        #pragma unroll
        for (int nt = 0; nt < 4; ++nt)
            Ob[base + nt * 16 + lcol] = f2bf(oacc[nt][r] * iv);
    }
}

// ====================== output GEMM v3: 3-buffer counted vmcnt, BK=32 ======================
// R9: transplant the R5-proven skeleton. Old v2 was the R4 disease (2-buffer
// __syncthreads -> vmcnt(0) drain every K-step) at only 8 waves/CU. v3: BK=32
// (32 steps), LDS 3 x (W 8KB + O 4KB) = 36KB -> 4 blocks/CU = 16 waves/CU;
// stage = 3 gl16/thread -> vmcnt(6) = 2 stages in flight (tail 3/0); fragment
// layout = qkv's proven 4-slot (row>>1)&3 swizzle; epilogue identical to v2.
// XCD remap: each XCD owns 4 n-tiles x 16 m-tiles (~3MB, L2-resident).
__global__ __launch_bounds__(256, 4) void out_gemm(
    const unsigned short* __restrict__ Ob,
    const unsigned short* __restrict__ Wto,
    const float* __restrict__ bo,
    float* __restrict__ out)
{
    __shared__ __align__(16) unsigned short Wld[3][128 * 32]; // out_n x k, 24 KB
    __shared__ __align__(16) unsigned short Old[3][64 * 32];  // token x k, 12 KB

    // XCD-balanced remap: 512 blocks; xcd k <- xe in {4(k&1)..}, ye in {16(k>>1)..}
    const int gid2 = blockIdx.x + 8 * blockIdx.y;   // 0..511; xcd = gid2&7
    const int xk = gid2 & 7, o = gid2 >> 3;         // o: 0..63
    const int xe = (xk & 1) * 4 + (o & 3);          // 0..7   (n-tile)
    const int ye = (xk >> 1) * 16 + (o >> 2);       // 0..63  (m-tile)
    const int m0g = ye * 64;    // tokens
    const int n0g = xe * 128;   // out_n

    const int wave = threadIdx.x >> 6, lane = threadIdx.x & 63;
    const int quad = lane >> 4, lcol = lane & 15;
    const int nb = wave * 32;           // wave's out_n sub-range

    f32x4 acc[2][4];
    #pragma unroll
    for (int i = 0; i < 2; ++i)
        #pragma unroll
        for (int j = 0; j < 4; ++j) acc[i][j] = (f32x4){0.f, 0.f, 0.f, 0.f};

    // stage one 32-wide K-slice: W 128 rows (2 gl16) + O 64 rows (1 gl16) = 3/thread
    auto stage = [&](int ks, int bf) {
        #pragma unroll
        for (int i = 0; i < 2; ++i) {
            int bi = i * 256 + threadIdx.x;
            int r = bi >> 2, p = (bi & 3) ^ ((r >> 1) & 3);
            gl16(Wto + (size_t)(n0g + r) * DD + ks + p * 8, &Wld[bf][(i * 4 + wave) * 512]);
        }
        {
            int bi = threadIdx.x;
            int r = bi >> 2, p = (bi & 3) ^ ((r >> 1) & 3);
            gl16(Ob + (size_t)(m0g + r) * DD + ks + p * 8, &Old[bf][wave * 512]);
        }
    };

    auto compute = [&](int bf) {
        bf16x8 wf[2], of[4];
        #pragma unroll
        for (int i = 0; i < 2; ++i) {
            int row = nb + i * 16 + lcol;
            wf[i] = ld_bf16x8(&Wld[bf][(row * 4 + (quad ^ ((row >> 1) & 3))) * 8]);
        }
        #pragma unroll
        for (int j = 0; j < 4; ++j) {
            int row = j * 16 + lcol;
            of[j] = ld_bf16x8(&Old[bf][(row * 4 + (quad ^ ((row >> 1) & 3))) * 8]);
        }
        #pragma unroll
        for (int i = 0; i < 2; ++i)
            #pragma unroll
            for (int j = 0; j < 4; ++j)
                acc[i][j] = __builtin_amdgcn_mfma_f32_16x16x32_bf16(wf[i], of[j], acc[i][j], 0, 0, 0);
    };

    stage(0, 0);
    stage(32, 1);

    // main loop: k = 0..29, buffers (k%3); vmcnt(6) = 2 stages (6 gl16) in flight
    for (int kk = 0; kk < 30; kk += 3) {
        #pragma unroll
        for (int u = 0; u < 3; ++u) {
            int k = kk + u;
            stage((k + 2) * 32, (u + 2) % 3);
            asm volatile("s_waitcnt vmcnt(6)" ::: "memory");
            __builtin_amdgcn_s_barrier();
            __builtin_amdgcn_sched_barrier(0);
            compute(u);
            __builtin_amdgcn_s_barrier();
        }
    }
    // k = 30 (buf 0): only stage(31) in flight
    asm volatile("s_waitcnt vmcnt(3)" ::: "memory");
    __builtin_amdgcn_s_barrier();
    __builtin_amdgcn_sched_barrier(0);
    compute(0);
    __builtin_amdgcn_s_barrier();
    // k = 31 (buf 1): drain
    asm volatile("s_waitcnt vmcnt(0)" ::: "memory");
    __builtin_amdgcn_s_barrier();
    __builtin_amdgcn_sched_barrier(0);
    compute(1);

    // C: col = token (lcol within j-tile), row = out_n (quad*4 + r, consecutive)
    #pragma unroll
    for (int i = 0; i < 2; ++i) {
        int n4 = n0g + nb + i * 16 + quad * 4;
        float4 bv4 = *(const float4*)&bo[n4];
        #pragma unroll
        for (int j = 0; j < 4; ++j) {
            int token = m0g + j * 16 + lcol;
            float4 o2;
            o2.x = acc[i][j][0] + bv4.x;
            o2.y = acc[i][j][1] + bv4.y;
            o2.z = acc[i][j][2] + bv4.z;
            o2.w = acc[i][j][3] + bv4.w;
            *(float4*)&out[(size_t)token * DD + n4] = o2;
        }
    }
}

extern "C" void kernel_launch(void* const* d_in, const int* in_sizes, int n_in,
                              void* d_out, int out_size, void* d_ws, size_t ws_size,
                              hipStream_t stream)
{
    const float* x  = (const float*)d_in[0];
    const float* Wq = (const float*)d_in[1];
    const float* bq = (const float*)d_in[2];
    const float* Wk = (const float*)d_in[3];
    const float* bk = (const float*)d_in[4];
    const float* Wv = (const float*)d_in[5];
    const float* bv = (const float*)d_in[6];
    const float* Wo = (const float*)d_in[7];
    const float* bo = (const float*)d_in[8];
    float* out = (float*)d_out;

    unsigned short* ws = (unsigned short*)d_ws;
    unsigned short* Wt  = ws;                        // 4 * D*D (q,k,v,o)
    unsigned short* Wto = Wt + 3 * (size_t)DD * DD;
    unsigned short* Qb  = Wt + 4 * (size_t)DD * DD;  // M*D each
    unsigned short* Kb  = Qb + (size_t)MM * DD;
    unsigned short* Vt  = Kb + (size_t)MM * DD;
    unsigned short* xb  = Vt + (size_t)MM * DD;      // total 40 MB
    unsigned short* Ob  = xb;                        // alias: xb dead after qkv_gemm

    prep<<<8192, 256, 0, stream>>>(x, xb, Wq, Wk, Wv, Wo, Wt);

    qkv_gemm<<<dim3(8, 32), 512, 0, stream>>>(xb, Wt, bq, bk, bv, Qb, Kb, Vt);

    attn<<<dim3(16, 32), 512, 0, stream>>>(Qb, Kb, Vt, Ob);

    out_gemm<<<dim3(8, 64), 256, 0, stream>>>(Ob, Wto, bo, out);
}